// Round 6
// baseline (172.583 us; speedup 1.0000x reference)
//
#include <hip/hip_runtime.h>
#include <cfloat>

#define NN   1024
#define NE   16384
#define D0   128
#define EDIM 16
#define NH1  64
#define NOUT 40
#define KTOP 8
#define NEGINF (-1000000000.0f)
#define MAXDEG 64   // out-deg ~ Poisson(16), gumbel in-deg ~ Poisson(8); P(>64) negligible

// ---- workspace layout (bytes); counters zeroed by one 8KB memset, rest written-before-read ----
#define OFF_CNTS  0u        // 1024 int (src list counts)   \ contiguous 8KB memset
#define OFF_CNTD  4096u     // 1024 int (dst list counts)   /
#define OFF_SE    8192u     // NE f
#define OFF_A     73728u    // 1024 f
#define OFF_B     77824u    // 1024 f
#define OFF_EM    81920u    // 8192 int
#define OFF_SLOTS 114688u   // 1024*64 int (src lists, fixed stride)
#define OFF_SLOTD 376832u   // 1024*64 int (dst lists, fixed stride)
#define OFF_H     638976u   // 1024*64 f

__device__ __forceinline__ void amx(float& v, int& j, float ov, int oj) {
    if (ov > v || (ov == v && oj < j)) { v = ov; j = oj; }
}

// blocks 0..63: se[e]=ea[e]@w_e + scatter edge into per-src list (parallel atomics);
// blocks 64..319: a,b row dots.
__global__ __launch_bounds__(256) void prep_kernel(
    const float* __restrict__ x, const float* __restrict__ ea,
    const float* __restrict__ mlp_w, const int* __restrict__ ei,
    float* __restrict__ se, float* __restrict__ a, float* __restrict__ b,
    int* __restrict__ cnt_src, int* __restrict__ slot_src)
{
    const int bid = blockIdx.x, t = threadIdx.x;
    if (bid < 64) {
        int e = bid * 256 + t;
        float acc = 0.f;
        #pragma unroll
        for (int k = 0; k < EDIM; k++) acc += ea[e * EDIM + k] * mlp_w[2 * D0 + k];
        se[e] = acc;
        int s = ei[e];
        int p = atomicAdd(&cnt_src[s], 1);
        if (p < MAXDEG) slot_src[s * MAXDEG + p] = e;  // order nondeterministic; consumer is max/min
    } else {
        int lane = t & 63, wid = t >> 6;
        int row = (bid - 64) * 4 + wid;
        const float* xr = x + row * D0;
        float x0 = xr[lane], x1 = xr[64 + lane];
        float sa = x0 * mlp_w[lane]       + x1 * mlp_w[64 + lane];
        float sb = x0 * mlp_w[128 + lane] + x1 * mlp_w[192 + lane];
        for (int s2 = 32; s2; s2 >>= 1) { sa += __shfl_down(sa, s2); sb += __shfl_down(sb, s2); }
        if (lane == 0) { a[row] = sa; b[row] = sb; }
    }
}

// One WAVE per row (4 rows / 256-thread block): barrier-free.
// Lane owns cells j = c*64+lane, c=0..15, in registers.
__global__ __launch_bounds__(256) void row_topk_kernel(
    const float* __restrict__ se, const float* __restrict__ mlp_b,
    const float* __restrict__ a, const float* __restrict__ b,
    const float* __restrict__ u, const int* __restrict__ ei,
    const int* __restrict__ cnt_src, const int* __restrict__ slot_src,
    int* __restrict__ em, int* __restrict__ cntd, int* __restrict__ slotd)
{
    __shared__ int idmx[4][NN];
    __shared__ int idmn[4][NN];
    const int t = threadIdx.x, lane = t & 63, wid = t >> 6;
    const int i = blockIdx.x * 4 + wid;
    const int rowoff = i * NN;
    const float bias = mlp_b[0];
    const float ai = a[i];

    // prefetch u early (used only after softmax) — overlaps score phase
    float uv[16];
    #pragma unroll
    for (int c = 0; c < 16; c++) uv[c] = u[rowoff + c * 64 + lane];

    #pragma unroll
    for (int c = 0; c < 16; c++) { idmx[wid][c * 64 + lane] = -1; idmn[wid][c * 64 + lane] = 0x7FFFFFFF; }
    __builtin_amdgcn_wave_barrier();
    int deg = min(cnt_src[i], MAXDEG);
    if (lane < deg) {
        int e = slot_src[i * MAXDEG + lane];
        int dj = ei[NE + e];
        atomicMax(&idmx[wid][dj], e);
        atomicMin(&idmn[wid][dj], e);
    }
    __builtin_amdgcn_wave_barrier();

    // scores (same per-element math as R5)
    float sv[16];
    float lmax = NEGINF;
    #pragma unroll
    for (int c = 0; c < 16; c++) {
        int j = c * 64 + lane;
        int id = idmx[wid][j];
        float s = (id >= 0) ? (((ai + b[j]) + se[id]) + bias) : NEGINF;
        sv[c] = s;
        lmax = fmaxf(lmax, s);
    }
    for (int s = 32; s; s >>= 1) lmax = fmaxf(lmax, __shfl_down(lmax, s));
    float rowmax = __shfl(lmax, 0);
    bool noedge = (rowmax == NEGINF);

    float lsum = 0.f;
    #pragma unroll
    for (int c = 0; c < 16; c++) {
        float evv;
        if (noedge) evv = 1.0f;
        else { float s = sv[c]; evv = (s == NEGINF) ? 0.0f : expf(s - rowmax); }
        sv[c] = evv;
        lsum += evv;
    }
    for (int s = 32; s; s >>= 1) lsum += __shfl_down(lsum, s);
    float rsum = __shfl(lsum, 0);

    #pragma unroll
    for (int c = 0; c < 16; c++) {
        float g = -logf(-logf(uv[c] + 1e-20f) + 1e-20f);
        sv[c] = sv[c] / rsum + g;
    }

    // iterative top-8, all in-wave
    int myj = 0;
    for (int sel = 0; sel < KTOP; sel++) {
        float bv = -FLT_MAX; int bj = NN;
        #pragma unroll
        for (int c = 0; c < 16; c++) amx(bv, bj, sv[c], c * 64 + lane);
        for (int s = 32; s; s >>= 1) {
            float ov = __shfl_down(bv, s); int oj = __shfl_down(bj, s);
            amx(bv, bj, ov, oj);
        }
        int bjw = __shfl(bj, 0);          // winner index, uniform
        if (lane == sel) myj = bjw;
        int rel = bjw - lane;
        #pragma unroll
        for (int c = 0; c < 16; c++) if (rel == c * 64) sv[c] = -FLT_MAX;
    }
    __builtin_amdgcn_wave_barrier();
    if (lane < KTOP) {
        int mn = idmn[wid][myj];
        em[i * KTOP + lane] = (mn == 0x7FFFFFFF) ? 0 : mn;
        int p = atomicAdd(&cntd[myj], 1);
        if (p < MAXDEG) slotd[myj * MAXDEG + p] = i * KTOP + lane;
    }
}

// GENConv1 fused, one WAVE per dst node (4 nodes / 256-thread block): barrier-free.
// Lane owns dims d and d+64 for agg; 4 MLP1 outputs; 1 MLP2 output.
__global__ __launch_bounds__(256) void genconv1_kernel(
    const float* __restrict__ x, const float* __restrict__ ea,
    const float* __restrict__ we_g, const float* __restrict__ be,
    const float* __restrict__ w1, const float* __restrict__ b1,
    const float* __restrict__ w2, const float* __restrict__ b2,
    const int* __restrict__ cntd, const int* __restrict__ slotd,
    const int* __restrict__ em, float* __restrict__ h)
{
    __shared__ int   slots[4][MAXDEG];
    __shared__ float eatt[4][MAXDEG * EDIM];
    __shared__ float arow[4][D0];
    __shared__ float t1s[4][2 * D0];
    const int t = threadIdx.x, lane = t & 63, wid = t >> 6;
    const int r = blockIdx.x * 4 + wid;
    const int cnt = min(cntd[r], MAXDEG);
    if (lane < cnt) slots[wid][lane] = slotd[r * MAXDEG + lane];
    __builtin_amdgcn_wave_barrier();
    if (lane == 0) {  // ascending-n order (deterministic)
        for (int p = 1; p < cnt; p++) {
            int v = slots[wid][p]; int q = p - 1;
            while (q >= 0 && slots[wid][q] > v) { slots[wid][q + 1] = slots[wid][q]; q--; }
            slots[wid][q + 1] = v;
        }
    }
    __builtin_amdgcn_wave_barrier();
    for (int q = lane; q < cnt * EDIM; q += 64)
        eatt[wid][q] = ea[em[slots[wid][q >> 4]] * EDIM + (q & 15)];
    __builtin_amdgcn_wave_barrier();

    const int dA = lane, dB = lane + 64;
    float wedA[EDIM], wedB[EDIM];
    #pragma unroll
    for (int k = 0; k < EDIM; k++) { wedA[k] = we_g[k * D0 + dA]; wedB[k] = we_g[k * D0 + dB]; }
    const float bedA = be[dA], bedB = be[dB];

    float mxA = -FLT_MAX, mxB = -FLT_MAX;
    for (int idx = 0; idx < cnt; idx++) {
        int src = slots[wid][idx] >> 3;
        float epA = bedA, epB = bedB;
        #pragma unroll
        for (int k = 0; k < EDIM; k++) {
            float ev = eatt[wid][idx * EDIM + k];
            epA += ev * wedA[k];
            epB += ev * wedB[k];
        }
        float mA = fmaxf(x[src * D0 + dA] + epA, 0.f) + 1e-7f;
        float mB = fmaxf(x[src * D0 + dB] + epB, 0.f) + 1e-7f;
        mxA = fmaxf(mxA, mA);
        mxB = fmaxf(mxB, mB);
    }
    float denA = 0.f, numA = 0.f, denB = 0.f, numB = 0.f;
    for (int idx = 0; idx < cnt; idx++) {
        int src = slots[wid][idx] >> 3;
        float epA = bedA, epB = bedB;
        #pragma unroll
        for (int k = 0; k < EDIM; k++) {
            float ev = eatt[wid][idx * EDIM + k];
            epA += ev * wedA[k];
            epB += ev * wedB[k];
        }
        float mA = fmaxf(x[src * D0 + dA] + epA, 0.f) + 1e-7f;
        float mB = fmaxf(x[src * D0 + dB] + epB, 0.f) + 1e-7f;
        float wA = expf(mA - mxA), wB = expf(mB - mxB);
        denA += wA; numA += wA * mA;
        denB += wB; numB += wB * mB;
    }
    float aggA = cnt ? numA / (denA > 0.f ? denA : 1.f) : 0.f;
    float aggB = cnt ? numB / (denB > 0.f ? denB : 1.f) : 0.f;
    arow[wid][dA] = aggA + x[r * D0 + dA];
    arow[wid][dB] = aggB + x[r * D0 + dB];
    __builtin_amdgcn_wave_barrier();

    // MLP1: 128 -> 256 relu; lane computes outputs lane+64c (k ascending: bit-identical per output)
    float acc[4];
    #pragma unroll
    for (int c = 0; c < 4; c++) acc[c] = b1[lane + 64 * c];
    for (int k = 0; k < D0; k++) {
        float av = arow[wid][k];
        #pragma unroll
        for (int c = 0; c < 4; c++) acc[c] += av * w1[k * 2 * D0 + lane + 64 * c];
    }
    #pragma unroll
    for (int c = 0; c < 4; c++) t1s[wid][lane + 64 * c] = fmaxf(acc[c], 0.f);
    __builtin_amdgcn_wave_barrier();

    // MLP2: 256 -> 64 relu
    float acc2 = b2[lane];
    for (int k = 0; k < 2 * D0; k++) acc2 += t1s[wid][k] * w2[k * NH1 + lane];
    h[r * NH1 + lane] = fmaxf(acc2, 0.f);
}

// GENConv2 fused + head, one WAVE per dst node (4 nodes / 256-thread block): barrier-free.
__global__ __launch_bounds__(256) void genconv2_kernel(
    const float* __restrict__ h, const float* __restrict__ ea,
    const float* __restrict__ we_g, const float* __restrict__ be,
    const float* __restrict__ w1, const float* __restrict__ b1,
    const float* __restrict__ w2, const float* __restrict__ b2,
    const float* __restrict__ fcw, const float* __restrict__ fcb,
    const int* __restrict__ cntd, const int* __restrict__ slotd,
    const int* __restrict__ em, const int* __restrict__ mask,
    float* __restrict__ out)
{
    __shared__ int   slots[4][MAXDEG];
    __shared__ float eatt[4][MAXDEG * EDIM];
    __shared__ float arow[4][NH1];
    __shared__ float t2s[4][2 * NH1];
    __shared__ float h2s[4][NH1];
    const int t = threadIdx.x, d = t & 63, wid = t >> 6;
    const int r = blockIdx.x * 4 + wid;
    const int cnt = min(cntd[r], MAXDEG);
    if (d < cnt) slots[wid][d] = slotd[r * MAXDEG + d];
    __builtin_amdgcn_wave_barrier();
    if (d == 0) {
        for (int p = 1; p < cnt; p++) {
            int v = slots[wid][p]; int q = p - 1;
            while (q >= 0 && slots[wid][q] > v) { slots[wid][q + 1] = slots[wid][q]; q--; }
            slots[wid][q + 1] = v;
        }
    }
    __builtin_amdgcn_wave_barrier();
    for (int q = d; q < cnt * EDIM; q += 64)
        eatt[wid][q] = ea[em[slots[wid][q >> 4]] * EDIM + (q & 15)];
    __builtin_amdgcn_wave_barrier();

    float wed[EDIM];
    #pragma unroll
    for (int k = 0; k < EDIM; k++) wed[k] = we_g[k * NH1 + d];
    const float bed = be[d];

    float mxv = -FLT_MAX;
    for (int idx = 0; idx < cnt; idx++) {
        int src = slots[wid][idx] >> 3;
        float ep = bed;
        #pragma unroll
        for (int k = 0; k < EDIM; k++) ep += eatt[wid][idx * EDIM + k] * wed[k];
        float m = fmaxf(h[src * NH1 + d] + ep, 0.f) + 1e-7f;
        mxv = fmaxf(mxv, m);
    }
    float den = 0.f, num = 0.f;
    for (int idx = 0; idx < cnt; idx++) {
        int src = slots[wid][idx] >> 3;
        float ep = bed;
        #pragma unroll
        for (int k = 0; k < EDIM; k++) ep += eatt[wid][idx * EDIM + k] * wed[k];
        float m = fmaxf(h[src * NH1 + d] + ep, 0.f) + 1e-7f;
        float w = expf(m - mxv);
        den += w; num += w * m;
    }
    float agg = cnt ? num / (den > 0.f ? den : 1.f) : 0.f;
    arow[wid][d] = agg + h[r * NH1 + d];
    __builtin_amdgcn_wave_barrier();

    {   // MLP1: 64 -> 128 relu (outputs d and d+64, k ascending: bit-identical)
        float acc_a = b1[d], acc_b = b1[d + NH1];
        for (int k = 0; k < NH1; k++) {
            float av = arow[wid][k];
            acc_a += av * w1[k * 2 * NH1 + d];
            acc_b += av * w1[k * 2 * NH1 + d + NH1];
        }
        t2s[wid][d] = fmaxf(acc_a, 0.f);
        t2s[wid][d + NH1] = fmaxf(acc_b, 0.f);
    }
    __builtin_amdgcn_wave_barrier();
    {
        float acc = b2[d];
        for (int k = 0; k < 2 * NH1; k++) acc += t2s[wid][k] * w2[k * NH1 + d];
        h2s[wid][d] = fmaxf(acc, 0.f);
    }
    __builtin_amdgcn_wave_barrier();
    if (d < NOUT) {
        float acc = fcb[d];
        for (int k = 0; k < NH1; k++) acc += h2s[wid][k] * fcw[k * NOUT + d];
        out[r * NOUT + d] = (mask[r] != 0) ? acc : 0.f;
    }
}

extern "C" void kernel_launch(void* const* d_in, const int* in_sizes, int n_in,
                              void* d_out, int out_size, void* d_ws, size_t ws_size,
                              hipStream_t stream) {
    const float* x      = (const float*)d_in[0];
    const float* ea     = (const float*)d_in[1];
    const float* u      = (const float*)d_in[2];
    const float* mlp_w  = (const float*)d_in[3];
    const float* mlp_b  = (const float*)d_in[4];
    const float* c1_we  = (const float*)d_in[5];
    const float* c1_be  = (const float*)d_in[6];
    const float* c1_w1  = (const float*)d_in[7];
    const float* c1_b1  = (const float*)d_in[8];
    const float* c1_w2  = (const float*)d_in[9];
    const float* c1_b2  = (const float*)d_in[10];
    const float* c2_we  = (const float*)d_in[11];
    const float* c2_be  = (const float*)d_in[12];
    const float* c2_w1  = (const float*)d_in[13];
    const float* c2_b1  = (const float*)d_in[14];
    const float* c2_w2  = (const float*)d_in[15];
    const float* c2_b2  = (const float*)d_in[16];
    const float* fc_w   = (const float*)d_in[17];
    const float* fc_b   = (const float*)d_in[18];
    const int*   ei     = (const int*)d_in[20];
    const int*   mask   = (const int*)d_in[21];

    char* ws = (char*)d_ws;
    int*   cnt_src = (int*)(ws + OFF_CNTS);
    int*   cntd    = (int*)(ws + OFF_CNTD);
    float* se      = (float*)(ws + OFF_SE);
    float* a       = (float*)(ws + OFF_A);
    float* b       = (float*)(ws + OFF_B);
    int*   em      = (int*)(ws + OFF_EM);
    int*   slot_s  = (int*)(ws + OFF_SLOTS);
    int*   slotd   = (int*)(ws + OFF_SLOTD);
    float* h       = (float*)(ws + OFF_H);
    float* out     = (float*)d_out;

    hipMemsetAsync(ws + OFF_CNTS, 0, 8192, stream);  // cnt_src + cntd
    prep_kernel<<<320, 256, 0, stream>>>(x, ea, mlp_w, ei, se, a, b, cnt_src, slot_s);
    row_topk_kernel<<<NN / 4, 256, 0, stream>>>(se, mlp_b, a, b, u, ei, cnt_src, slot_s,
                                                em, cntd, slotd);
    genconv1_kernel<<<NN / 4, 256, 0, stream>>>(x, ea, c1_we, c1_be, c1_w1, c1_b1, c1_w2, c1_b2,
                                                cntd, slotd, em, h);
    genconv2_kernel<<<NN / 4, 256, 0, stream>>>(h, ea, c2_we, c2_be, c2_w1, c2_b1, c2_w2, c2_b2,
                                                fc_w, fc_b, cntd, slotd, em, mask, out);
}

// Round 7
// 157.332 us; speedup vs baseline: 1.0969x; 1.0969x over previous
//
#include <hip/hip_runtime.h>
#include <cfloat>

#define NN   1024
#define NE   16384
#define D0   128
#define EDIM 16
#define NH1  64
#define NOUT 40
#define KTOP 8
#define NEGINF (-1000000000.0f)
#define MAXDEG 64   // out-deg ~ Poisson(16), gumbel in-deg ~ Poisson(8); P(>64) negligible

// ---- workspace layout (bytes); counters zeroed by one 8KB memset, rest written-before-read ----
#define OFF_CNTS  0u        // 1024 int (src list counts)   \ contiguous 8KB memset
#define OFF_CNTD  4096u     // 1024 int (dst list counts)   /
#define OFF_SE    8192u     // NE f
#define OFF_A     73728u    // 1024 f
#define OFF_B     77824u    // 1024 f
#define OFF_EM    81920u    // 8192 int
#define OFF_SLOTS 114688u   // 1024*64 int (src lists, fixed stride)
#define OFF_SLOTD 376832u   // 1024*64 int (dst lists, fixed stride)
#define OFF_H     638976u   // 1024*64 f

__device__ __forceinline__ void amx(float& v, int& j, float ov, int oj) {
    if (ov > v || (ov == v && oj < j)) { v = ov; j = oj; }
}

// blocks 0..63: se[e]=ea[e]@w_e + scatter edge into per-src list (parallel atomics);
// blocks 64..319: a,b row dots.
__global__ __launch_bounds__(256) void prep_kernel(
    const float* __restrict__ x, const float* __restrict__ ea,
    const float* __restrict__ mlp_w, const int* __restrict__ ei,
    float* __restrict__ se, float* __restrict__ a, float* __restrict__ b,
    int* __restrict__ cnt_src, int* __restrict__ slot_src)
{
    const int bid = blockIdx.x, t = threadIdx.x;
    if (bid < 64) {
        int e = bid * 256 + t;
        float acc = 0.f;
        #pragma unroll
        for (int k = 0; k < EDIM; k++) acc += ea[e * EDIM + k] * mlp_w[2 * D0 + k];
        se[e] = acc;
        int s = ei[e];
        int p = atomicAdd(&cnt_src[s], 1);
        if (p < MAXDEG) slot_src[s * MAXDEG + p] = e;  // order nondeterministic; consumer is max/min
    } else {
        int lane = t & 63, wid = t >> 6;
        int row = (bid - 64) * 4 + wid;
        const float* xr = x + row * D0;
        float x0 = xr[lane], x1 = xr[64 + lane];
        float sa = x0 * mlp_w[lane]       + x1 * mlp_w[64 + lane];
        float sb = x0 * mlp_w[128 + lane] + x1 * mlp_w[192 + lane];
        for (int s2 = 32; s2; s2 >>= 1) { sa += __shfl_down(sa, s2); sb += __shfl_down(sb, s2); }
        if (lane == 0) { a[row] = sa; b[row] = sb; }
    }
}

// Block per row (4 waves, high TLP). Cells live in registers (rv[4], j = t + q*256).
// Softmax reductions: exact R5 order (per-thread q-ascending -> shfl -> wred[0..3]).
// Top-8: per-wave local top-8 in registers (no barriers), then wave 0 merges 32 candidates.
__global__ __launch_bounds__(256) void row_topk_kernel(
    const float* __restrict__ se, const float* __restrict__ mlp_b,
    const float* __restrict__ a, const float* __restrict__ b,
    const float* __restrict__ u, const int* __restrict__ ei,
    const int* __restrict__ cnt_src, const int* __restrict__ slot_src,
    int* __restrict__ em, int* __restrict__ cntd, int* __restrict__ slotd)
{
    __shared__ int   idmx[NN];
    __shared__ int   idmn[NN];
    __shared__ float wred[4];
    __shared__ float cand_v[4 * KTOP];
    __shared__ int   cand_j[4 * KTOP];
    const int i = blockIdx.x, t = threadIdx.x;
    const int lane = t & 63, wid = t >> 6;
    const int rowoff = i * NN;
    const float bias = mlp_b[0];
    const float ai = a[i];

    #pragma unroll
    for (int q = 0; q < 4; q++) { int j = t + q * 256; idmx[j] = -1; idmn[j] = 0x7FFFFFFF; }
    __syncthreads();
    int deg = min(cnt_src[i], MAXDEG);
    if (t < deg) {
        int e = slot_src[i * MAXDEG + t];
        int dj = ei[NE + e];
        atomicMax(&idmx[dj], e);
        atomicMin(&idmn[dj], e);
    }
    __syncthreads();

    float rv[4];
    float lmax = NEGINF;
    #pragma unroll
    for (int q = 0; q < 4; q++) {
        int j = t + q * 256;
        int id = idmx[j];
        float s = (id >= 0) ? (((ai + b[j]) + se[id]) + bias) : NEGINF;
        rv[q] = s;
        lmax = fmaxf(lmax, s);
    }
    for (int s = 32; s; s >>= 1) lmax = fmaxf(lmax, __shfl_down(lmax, s));
    if (lane == 0) wred[wid] = lmax;
    __syncthreads();
    float rowmax = fmaxf(fmaxf(wred[0], wred[1]), fmaxf(wred[2], wred[3]));
    bool noedge = (rowmax == NEGINF);
    __syncthreads();

    float lsum = 0.f;
    #pragma unroll
    for (int q = 0; q < 4; q++) {
        float evv;
        if (noedge) evv = 1.0f;
        else { float s = rv[q]; evv = (s == NEGINF) ? 0.0f : expf(s - rowmax); }
        rv[q] = evv;
        lsum += evv;
    }
    for (int s = 32; s; s >>= 1) lsum += __shfl_down(lsum, s);
    if (lane == 0) wred[wid] = lsum;
    __syncthreads();
    float rsum = wred[0] + wred[1] + wred[2] + wred[3];

    #pragma unroll
    for (int q = 0; q < 4; q++) {
        int j = t + q * 256;
        float z = rv[q] / rsum;
        float uu = u[rowoff + j];
        float g = -logf(-logf(uu + 1e-20f) + 1e-20f);
        rv[q] = z + g;
    }

    // per-wave local top-8 (registers + shfl only; global top-8 subset of union of these)
    float cv = -FLT_MAX; int cj = NN;
    for (int sel = 0; sel < KTOP; sel++) {
        float bv = -FLT_MAX; int bj = NN;
        #pragma unroll
        for (int q = 0; q < 4; q++) amx(bv, bj, rv[q], t + q * 256);
        for (int s = 32; s; s >>= 1) {
            float ov = __shfl_down(bv, s); int oj = __shfl_down(bj, s);
            amx(bv, bj, ov, oj);
        }
        float bvw = __shfl(bv, 0); int bjw = __shfl(bj, 0);
        if (lane == sel) { cv = bvw; cj = bjw; }
        #pragma unroll
        for (int q = 0; q < 4; q++) if (t + q * 256 == bjw) rv[q] = -FLT_MAX;
    }
    if (lane < KTOP) { cand_v[wid * KTOP + lane] = cv; cand_j[wid * KTOP + lane] = cj; }
    __syncthreads();

    // wave 0 merges the 32 candidates -> global top-8 (same (v, min-j) tie-break)
    if (wid == 0) {
        float mv = (lane < 4 * KTOP) ? cand_v[lane] : -FLT_MAX;
        int   mj = (lane < 4 * KTOP) ? cand_j[lane] : NN;
        int myj = 0;
        for (int sel = 0; sel < KTOP; sel++) {
            float bv = mv; int bj = mj;
            for (int s = 32; s; s >>= 1) {
                float ov = __shfl_down(bv, s); int oj = __shfl_down(bj, s);
                amx(bv, bj, ov, oj);
            }
            int bjw = __shfl(bj, 0);
            if (lane == sel) myj = bjw;
            if (mj == bjw) mv = -FLT_MAX;   // j unique across candidates
        }
        if (lane < KTOP) {
            int mn = idmn[myj];
            em[i * KTOP + lane] = (mn == 0x7FFFFFFF) ? 0 : mn;
            int p = atomicAdd(&cntd[myj], 1);
            if (p < MAXDEG) slotd[myj * MAXDEG + p] = i * KTOP + lane;
        }
    }
}

// GENConv1 fused: 2 dst nodes per 256-thread block. d = t&127, sub = t>>7.  (R5 version)
__global__ __launch_bounds__(256) void genconv1_kernel(
    const float* __restrict__ x, const float* __restrict__ ea,
    const float* __restrict__ we_g, const float* __restrict__ be,
    const float* __restrict__ w1, const float* __restrict__ b1,
    const float* __restrict__ w2, const float* __restrict__ b2,
    const int* __restrict__ cntd, const int* __restrict__ slotd,
    const int* __restrict__ em, float* __restrict__ h)
{
    __shared__ int   slots[2][MAXDEG];
    __shared__ float eatt[2][MAXDEG * EDIM];
    __shared__ float arow[2][D0];
    __shared__ float t1s[2][2 * D0];
    const int t = threadIdx.x, sub = t >> 7, d = t & 127;
    const int r = blockIdx.x * 2 + sub;
    const int cnt = min(cntd[r], MAXDEG);
    if (d < cnt) slots[sub][d] = slotd[r * MAXDEG + d];
    __syncthreads();
    if (d == 0) {  // ascending-n order (deterministic)
        for (int p = 1; p < cnt; p++) {
            int v = slots[sub][p]; int q = p - 1;
            while (q >= 0 && slots[sub][q] > v) { slots[sub][q + 1] = slots[sub][q]; q--; }
            slots[sub][q + 1] = v;
        }
    }
    __syncthreads();
    for (int q = d; q < cnt * EDIM; q += 128)
        eatt[sub][q] = ea[em[slots[sub][q >> 4]] * EDIM + (q & 15)];
    __syncthreads();

    float wed[EDIM];
    #pragma unroll
    for (int k = 0; k < EDIM; k++) wed[k] = we_g[k * D0 + d];
    const float bed = be[d];

    float mxv = -FLT_MAX;
    for (int idx = 0; idx < cnt; idx++) {
        int src = slots[sub][idx] >> 3;
        float ep = bed;
        #pragma unroll
        for (int k = 0; k < EDIM; k++) ep += eatt[sub][idx * EDIM + k] * wed[k];
        float m = fmaxf(x[src * D0 + d] + ep, 0.f) + 1e-7f;
        mxv = fmaxf(mxv, m);
    }
    float den = 0.f, num = 0.f;
    for (int idx = 0; idx < cnt; idx++) {
        int src = slots[sub][idx] >> 3;
        float ep = bed;
        #pragma unroll
        for (int k = 0; k < EDIM; k++) ep += eatt[sub][idx * EDIM + k] * wed[k];
        float m = fmaxf(x[src * D0 + d] + ep, 0.f) + 1e-7f;
        float w = expf(m - mxv);
        den += w; num += w * m;
    }
    float agg = cnt ? num / (den > 0.f ? den : 1.f) : 0.f;
    arow[sub][d] = agg + x[r * D0 + d];
    __syncthreads();

    float acc0 = b1[d], acc1 = b1[d + D0];
    for (int k = 0; k < D0; k++) {
        float av = arow[sub][k];
        acc0 += av * w1[k * 2 * D0 + d];
        acc1 += av * w1[k * 2 * D0 + d + D0];
    }
    t1s[sub][d] = fmaxf(acc0, 0.f);
    t1s[sub][d + D0] = fmaxf(acc1, 0.f);
    __syncthreads();
    if (d < NH1) {
        float acc = b2[d];
        for (int k = 0; k < 2 * D0; k++) acc += t1s[sub][k] * w2[k * NH1 + d];
        h[r * NH1 + d] = fmaxf(acc, 0.f);
    }
}

// GENConv2 fused + head: 4 dst nodes per 256-thread block. d = t&63, sub = t>>6.  (R5 version)
__global__ __launch_bounds__(256) void genconv2_kernel(
    const float* __restrict__ h, const float* __restrict__ ea,
    const float* __restrict__ we_g, const float* __restrict__ be,
    const float* __restrict__ w1, const float* __restrict__ b1,
    const float* __restrict__ w2, const float* __restrict__ b2,
    const float* __restrict__ fcw, const float* __restrict__ fcb,
    const int* __restrict__ cntd, const int* __restrict__ slotd,
    const int* __restrict__ em, const int* __restrict__ mask,
    float* __restrict__ out)
{
    __shared__ int   slots[4][MAXDEG];
    __shared__ float eatt[4][MAXDEG * EDIM];
    __shared__ float arow[4][NH1];
    __shared__ float t2s[4][2 * NH1];
    __shared__ float h2s[4][NH1];
    const int t = threadIdx.x, sub = t >> 6, d = t & 63;
    const int r = blockIdx.x * 4 + sub;
    const int cnt = min(cntd[r], MAXDEG);
    if (d < cnt) slots[sub][d] = slotd[r * MAXDEG + d];
    __syncthreads();
    if (d == 0) {
        for (int p = 1; p < cnt; p++) {
            int v = slots[sub][p]; int q = p - 1;
            while (q >= 0 && slots[sub][q] > v) { slots[sub][q + 1] = slots[sub][q]; q--; }
            slots[sub][q + 1] = v;
        }
    }
    __syncthreads();
    for (int q = d; q < cnt * EDIM; q += 64)
        eatt[sub][q] = ea[em[slots[sub][q >> 4]] * EDIM + (q & 15)];
    __syncthreads();

    float wed[EDIM];
    #pragma unroll
    for (int k = 0; k < EDIM; k++) wed[k] = we_g[k * NH1 + d];
    const float bed = be[d];

    float mxv = -FLT_MAX;
    for (int idx = 0; idx < cnt; idx++) {
        int src = slots[sub][idx] >> 3;
        float ep = bed;
        #pragma unroll
        for (int k = 0; k < EDIM; k++) ep += eatt[sub][idx * EDIM + k] * wed[k];
        float m = fmaxf(h[src * NH1 + d] + ep, 0.f) + 1e-7f;
        mxv = fmaxf(mxv, m);
    }
    float den = 0.f, num = 0.f;
    for (int idx = 0; idx < cnt; idx++) {
        int src = slots[sub][idx] >> 3;
        float ep = bed;
        #pragma unroll
        for (int k = 0; k < EDIM; k++) ep += eatt[sub][idx * EDIM + k] * wed[k];
        float m = fmaxf(h[src * NH1 + d] + ep, 0.f) + 1e-7f;
        float w = expf(m - mxv);
        den += w; num += w * m;
    }
    float agg = cnt ? num / (den > 0.f ? den : 1.f) : 0.f;
    arow[sub][d] = agg + h[r * NH1 + d];
    __syncthreads();

    {
        float acc_a = b1[d], acc_b = b1[d + NH1];
        for (int k = 0; k < NH1; k++) {
            float av = arow[sub][k];
            acc_a += av * w1[k * 2 * NH1 + d];
            acc_b += av * w1[k * 2 * NH1 + d + NH1];
        }
        t2s[sub][d] = fmaxf(acc_a, 0.f);
        t2s[sub][d + NH1] = fmaxf(acc_b, 0.f);
    }
    __syncthreads();
    {
        float acc = b2[d];
        for (int k = 0; k < 2 * NH1; k++) acc += t2s[sub][k] * w2[k * NH1 + d];
        h2s[sub][d] = fmaxf(acc, 0.f);
    }
    __syncthreads();
    if (d < NOUT) {
        float acc = fcb[d];
        for (int k = 0; k < NH1; k++) acc += h2s[sub][k] * fcw[k * NOUT + d];
        out[r * NOUT + d] = (mask[r] != 0) ? acc : 0.f;
    }
}

extern "C" void kernel_launch(void* const* d_in, const int* in_sizes, int n_in,
                              void* d_out, int out_size, void* d_ws, size_t ws_size,
                              hipStream_t stream) {
    const float* x      = (const float*)d_in[0];
    const float* ea     = (const float*)d_in[1];
    const float* u      = (const float*)d_in[2];
    const float* mlp_w  = (const float*)d_in[3];
    const float* mlp_b  = (const float*)d_in[4];
    const float* c1_we  = (const float*)d_in[5];
    const float* c1_be  = (const float*)d_in[6];
    const float* c1_w1  = (const float*)d_in[7];
    const float* c1_b1  = (const float*)d_in[8];
    const float* c1_w2  = (const float*)d_in[9];
    const float* c1_b2  = (const float*)d_in[10];
    const float* c2_we  = (const float*)d_in[11];
    const float* c2_be  = (const float*)d_in[12];
    const float* c2_w1  = (const float*)d_in[13];
    const float* c2_b1  = (const float*)d_in[14];
    const float* c2_w2  = (const float*)d_in[15];
    const float* c2_b2  = (const float*)d_in[16];
    const float* fc_w   = (const float*)d_in[17];
    const float* fc_b   = (const float*)d_in[18];
    const int*   ei     = (const int*)d_in[20];
    const int*   mask   = (const int*)d_in[21];

    char* ws = (char*)d_ws;
    int*   cnt_src = (int*)(ws + OFF_CNTS);
    int*   cntd    = (int*)(ws + OFF_CNTD);
    float* se      = (float*)(ws + OFF_SE);
    float* a       = (float*)(ws + OFF_A);
    float* b       = (float*)(ws + OFF_B);
    int*   em      = (int*)(ws + OFF_EM);
    int*   slot_s  = (int*)(ws + OFF_SLOTS);
    int*   slotd   = (int*)(ws + OFF_SLOTD);
    float* h       = (float*)(ws + OFF_H);
    float* out     = (float*)d_out;

    hipMemsetAsync(ws + OFF_CNTS, 0, 8192, stream);  // cnt_src + cntd
    prep_kernel<<<320, 256, 0, stream>>>(x, ea, mlp_w, ei, se, a, b, cnt_src, slot_s);
    row_topk_kernel<<<NN, 256, 0, stream>>>(se, mlp_b, a, b, u, ei, cnt_src, slot_s,
                                            em, cntd, slotd);
    genconv1_kernel<<<NN / 2, 256, 0, stream>>>(x, ea, c1_we, c1_be, c1_w1, c1_b1, c1_w2, c1_b2,
                                                cntd, slotd, em, h);
    genconv2_kernel<<<NN / 4, 256, 0, stream>>>(h, ea, c2_we, c2_be, c2_w1, c2_b1, c2_w2, c2_b2,
                                                fc_w, fc_b, cntd, slotd, em, mask, out);
}